// Round 5
// baseline (215.133 us; speedup 1.0000x reference)
//
#include <hip/hip_runtime.h>
#include <stdint.h>

typedef unsigned short u16;
typedef short s16x8 __attribute__((ext_vector_type(8)));
typedef float f32x4 __attribute__((ext_vector_type(4)));

#define SQ 2048
#define DH 64
#define BN 64
#define STR 72             // prep-only LDS transpose stride (shorts)
#define PSTR 72            // P row stride (shorts): 144B -> 2-way bank alias = free
#define SPECIAL_START 2040
#define NBH 32             // b*h
#define NKV 8              // b*hk
#define NITEMS 2048        // (bh, 32-row q tile) work items, popped per-WAVE
#define ATTN_BLOCKS 768    // 3 blocks/CU x 4 waves = 12 waves/CU resident
// softclamp+softmax folded to exp2: p = 2^( t*poly(t*t) - KEF ), t = s * K1F
#define K1F  0.18033688011112043f    // 0.125 * log2(e)
#define KPAF 4.9244826e-9f           // (2/15)*k^2, k = (0.02/log2e)^2
#define KPBF -6.406040185576019e-5f  // -k/3
#define KEF  36.067376022224085f     // 25 * log2(e)  (constant softmax shift = 25)

union U8 { s16x8 v; short e[8]; };
union F4 { f32x4 v; float e[4]; };

__device__ __forceinline__ u16 f2bf(float x) {  // round-to-nearest-even
    uint32_t u = __float_as_uint(x);
    return (u16)((u + 0x7fffu + ((u >> 16) & 1u)) >> 16);
}
__device__ __forceinline__ uint32_t pkbf(float a, float b) {  // pack 2 bf16, 1 instr
    uint32_t r;
    asm("v_cvt_pk_bf16_f32 %0, %1, %2" : "=v"(r) : "v"(a), "v"(b));
    return r;
}
__device__ __forceinline__ float exp2hw(float x) {
    float r; asm("v_exp_f32 %0, %1" : "=v"(r) : "v"(x)); return r;
}
__device__ __forceinline__ float2 fsincos(float ang) {  // {sin, cos}, fast HW path
    float r = ang * 0.15915494309189535f;   // radians -> revolutions
    r -= floorf(r);
    float s, c;
    asm("v_sin_f32 %0, %1" : "=v"(s) : "v"(r));
    asm("v_cos_f32 %0, %1" : "=v"(c) : "v"(r));
    return make_float2(s, c);
}

// ---- prep: V tiles (transpose to [tile][d][kv]) + K rope rows (bf16) ----
#define VTILES (NKV * 32)                 // 256 tile-blocks
#define RK (NKV * SQ)                     // 16384 K rows
#define KBLK (RK / 32)                    // 512 row-blocks (32 rows each)
__global__ __launch_bounds__(256)
void prep_kernel(const float* __restrict__ kg, const float* __restrict__ vg,
                 const float* __restrict__ rotg,
                 u16* __restrict__ kp, u16* __restrict__ vp,
                 uint32_t* __restrict__ cnt)
{
    const int tid = threadIdx.x;
    if (blockIdx.x == 0 && tid == 0) *cnt = 0u;
    if (blockIdx.x < VTILES) {
        __shared__ short Vls[64 * STR];
        const int tile = blockIdx.x;                   // bkv*32 + kt
        const float* src = vg + ((size_t)(tile >> 5) * SQ + (size_t)(tile & 31) * 64) * DH;
        {
            int kv = tid >> 2, c0 = (tid & 3) * 16;
            const float* s4 = src + (size_t)kv * DH + c0;
            float4 f0 = *(const float4*)(s4);
            float4 f1 = *(const float4*)(s4 + 4);
            float4 f2 = *(const float4*)(s4 + 8);
            float4 f3 = *(const float4*)(s4 + 12);
            uint4 w0 = make_uint4(pkbf(f0.x, f0.y), pkbf(f0.z, f0.w),
                                  pkbf(f1.x, f1.y), pkbf(f1.z, f1.w));
            uint4 w1 = make_uint4(pkbf(f2.x, f2.y), pkbf(f2.z, f2.w),
                                  pkbf(f3.x, f3.y), pkbf(f3.z, f3.w));
            *(uint4*)&Vls[kv * STR + c0]     = w0;
            *(uint4*)&Vls[kv * STR + c0 + 8] = w1;
        }
        __syncthreads();
        {
            int d = tid >> 2, c0 = (tid & 3) * 16;
            U8 o0, o1;
#pragma unroll
            for (int j = 0; j < 16; j++)
                (j < 8 ? o0 : o1).e[j & 7] = Vls[(c0 + j) * STR + d];  // transpose
            u16* dst = vp + (((size_t)tile * 64 + d) << 6) + c0;
            *(s16x8*)dst       = o0.v;
            *(s16x8*)(dst + 8) = o1.v;
        }
    } else {
        int bx = blockIdx.x - VTILES;
        int r8 = tid >> 3, c0 = (tid & 7) * 4;      // c0 in 0..28 (<32)
        int r = bx * 32 + r8;                        // r in [0, RK)
        const int s = r & (SQ - 1);
        const float* src = kg + (size_t)r * DH;
        u16*         dst = kp + (size_t)r * DH;
        float4 a  = *(const float4*)(src + c0);
        float4 b  = *(const float4*)(src + c0 + 32);
        float4 rv = *(const float4*)(rotg + (size_t)s * DH + c0);
        float2 s0 = fsincos(rv.x), s1 = fsincos(rv.y),
               s2 = fsincos(rv.z), s3 = fsincos(rv.w);
        float lo0 = a.x * s0.y - b.x * s0.x, hi0 = b.x * s0.y + a.x * s0.x;
        float lo1 = a.y * s1.y - b.y * s1.x, hi1 = b.y * s1.y + a.y * s1.x;
        float lo2 = a.z * s2.y - b.z * s2.x, hi2 = b.z * s2.y + a.z * s2.x;
        float lo3 = a.w * s3.y - b.w * s3.x, hi3 = b.w * s3.y + a.w * s3.x;
        *(uint2*)(dst + c0)      = make_uint2(pkbf(lo0, lo1), pkbf(lo2, lo3));
        *(uint2*)(dst + c0 + 32) = make_uint2(pkbf(hi0, hi1), pkbf(hi2, hi3));
    }
}

// ---- attn: fully independent waves, ZERO barriers. Each wave owns 32 q-rows
// of one (bh, q-tile) item, pops items from a global queue at wave scope.
// K/V fragments stream from L2-resident kp/vp straight into REGISTERS with a
// one-tile prefetch distance (AITER-style counted-vmcnt pipeline; possible at
// source level only because there are no barriers to drain). LDS holds only
// the wave-private padded P round-trip (2-way alias = conflict-free).
// S^T = K.Q^T via mfma(A=K,B=Q)   -> C: col(l15)=q, row(quad*4+c)=kv
// O^T = V^T.P via mfma(A=Vt,B=P)  -> C: col(l15)=q, row(quad*4+c)=d
__global__ __launch_bounds__(256)
__attribute__((amdgpu_waves_per_eu(3, 3)))
void attn_fast(const float* __restrict__ qg, const float* __restrict__ rotg,
               const u16* __restrict__ kp, const u16* __restrict__ vp,
               uint32_t* __restrict__ cnt, float* __restrict__ outg)
{
    const int lane = threadIdx.x & 63;
    const int wv   = threadIdx.x >> 6;
    const int l15 = lane & 15, quad = lane >> 4;

    __shared__ __align__(16) short Ps[4][32 * PSTR];   // 18 KB, wave-private rows
    short* prow0 = &Ps[wv][l15 * PSTR];
    short* prow1 = &Ps[wv][(16 + l15) * PSTR];

    for (;;) {
        int w = 0;
        if (lane == 0) w = (int)atomicAdd(cnt, 1u);
        w = __shfl(w, 0, 64);
        if (w >= NITEMS) break;
        const int idx = 63 - (w >> 5);             // heavy-first (nkt descending)
        const int u   = w & 31, bkv = u >> 2;      // consecutive pops share bkv
        const int bh  = ((bkv >> 2) << 4) | ((bkv & 3) << 2) | (u & 3);
        const int qs  = idx * 32;
        const int nkt = ((idx >> 3) + 1) << 2;     // block-causal tiles: 4..32

        // per-lane fragment bases (kp and vp share the same [2048][64] stride)
        const u16* kptr = kp + (size_t)bkv * (SQ * DH) + l15 * DH + quad * 8;
        const u16* vptr = vp + (size_t)bkv * (SQ * DH) + l15 * DH + quad * 8;

        // ---- register-resident K/V fragments, one tile in flight ----
        s16x8 kf0[4], kf1[4], vf0[4], vf1[4];      // [mb], ks split 0/1
        auto loadK = [&](int kt) {
            const u16* p = kptr + ((size_t)kt << 12);
#pragma unroll
            for (int mb = 0; mb < 4; mb++) {
                kf0[mb] = *(const s16x8*)(p + mb * 1024);
                kf1[mb] = *(const s16x8*)(p + mb * 1024 + 32);
            }
        };
        auto loadV = [&](int kt) {
            const u16* p = vptr + ((size_t)kt << 12);
#pragma unroll
            for (int mb = 0; mb < 4; mb++) {
                vf0[mb] = *(const s16x8*)(p + mb * 1024);
                vf1[mb] = *(const s16x8*)(p + mb * 1024 + 32);
            }
        };
        loadK(0);
        loadV(0);

        // ---- Q rope -> registers (L2 latency of loadK/loadV hides under this) ----
        s16x8 qf[2][2];
#pragma unroll
        for (int nq = 0; nq < 2; nq++) {
            const int srow = qs + nq * 16 + l15;
            const float* gq = qg + ((size_t)bh * SQ + srow) * DH + quad * 8;
            float a[8], b[8];
            *(float4*)&a[0] = *(const float4*)(gq);
            *(float4*)&a[4] = *(const float4*)(gq + 4);
            *(float4*)&b[0] = *(const float4*)(gq + 32);
            *(float4*)&b[4] = *(const float4*)(gq + 36);
            const float* rrow = rotg + (size_t)srow * DH + quad * 8;
            float lo[8], hi[8];
#pragma unroll
            for (int j = 0; j < 8; j++) {
                float2 sc = fsincos(rrow[j]);
                lo[j] = a[j] * sc.y - b[j] * sc.x;
                hi[j] = b[j] * sc.y + a[j] * sc.x;
            }
            U8 q0, q1;
#pragma unroll
            for (int j = 0; j < 4; j++) {
                ((uint32_t*)&q0.v)[j] = pkbf(lo[2 * j], lo[2 * j + 1]);
                ((uint32_t*)&q1.v)[j] = pkbf(hi[2 * j], hi[2 * j + 1]);
            }
            qf[nq][0] = q0.v;
            qf[nq][1] = q1.v;
        }

        F4 oa0[4], oa1[4], lsa0, lsa1;
#pragma unroll
        for (int mb = 0; mb < 4; mb++) {
            oa0[mb].v = (f32x4){0.f, 0.f, 0.f, 0.f};
            oa1[mb].v = (f32x4){0.f, 0.f, 0.f, 0.f};
        }
        lsa0.v = (f32x4){0.f, 0.f, 0.f, 0.f};
        lsa1.v = (f32x4){0.f, 0.f, 0.f, 0.f};

        for (int kt = 0; kt < nkt; kt++) {
            // ---- QK^T: S^T[kv][q]; kf was prefetched last iteration ----
            F4 sa0[4], sa1[4];
            __builtin_amdgcn_s_setprio(1);
#pragma unroll
            for (int mb = 0; mb < 4; mb++) {
                sa0[mb].v = __builtin_amdgcn_mfma_f32_16x16x32_bf16(
                    kf0[mb], qf[0][0], (f32x4){0.f, 0.f, 0.f, 0.f}, 0, 0, 0);
                sa1[mb].v = __builtin_amdgcn_mfma_f32_16x16x32_bf16(
                    kf0[mb], qf[1][0], (f32x4){0.f, 0.f, 0.f, 0.f}, 0, 0, 0);
            }
#pragma unroll
            for (int mb = 0; mb < 4; mb++) {
                sa0[mb].v = __builtin_amdgcn_mfma_f32_16x16x32_bf16(
                    kf1[mb], qf[0][1], sa0[mb].v, 0, 0, 0);
                sa1[mb].v = __builtin_amdgcn_mfma_f32_16x16x32_bf16(
                    kf1[mb], qf[1][1], sa1[mb].v, 0, 0, 0);
            }
            __builtin_amdgcn_s_setprio(0);
            if (kt + 1 < nkt) loadK(kt + 1);   // overwrite kf; WAR after last use

            // ---- softclamp + constant-shift softmax (vectorized -> v_pk_*) ----
            const int last = (kt == 31);
#pragma unroll
            for (int nq = 0; nq < 2; nq++) {
                const int qglob = qs + nq * 16 + l15;
                short* prow = nq ? prow1 : prow0;
#pragma unroll
                for (int mb = 0; mb < 4; mb++) {
                    F4 t, w2, py, pa;
                    t.v  = (nq ? sa1[mb].v : sa0[mb].v) * K1F;
                    w2.v = t.v * t.v;
                    py.v = w2.v * KPAF + KPBF;
                    py.v = w2.v * py.v + 1.0f;
                    t.v  = t.v * py.v - KEF;
                    pa.e[0] = exp2hw(t.e[0]);
                    pa.e[1] = exp2hw(t.e[1]);
                    pa.e[2] = exp2hw(t.e[2]);
                    pa.e[3] = exp2hw(t.e[3]);
                    if (last && qglob < SPECIAL_START) {   // special-token mask
#pragma unroll
                        for (int c = 0; c < 4; c++) {
                            int kvglob = kt * BN + mb * 16 + quad * 4 + c;
                            if (kvglob >= SPECIAL_START) pa.e[c] = 0.f;
                        }
                    }
                    if (nq) lsa1.v = lsa1.v + pa.v; else lsa0.v = lsa0.v + pa.v;
                    uint2 pw = make_uint2(pkbf(pa.e[0], pa.e[1]),
                                          pkbf(pa.e[2], pa.e[3]));
                    *(uint2*)&prow[mb * 16 + quad * 4] = pw;   // wave-private
                }
            }

            // ---- PV: O^T[d][q] += Vt.P; vf was prefetched last iteration ----
            s16x8 pf00 = *(const s16x8*)&prow0[quad * 8];
            s16x8 pf01 = *(const s16x8*)&prow0[32 + quad * 8];
            s16x8 pf10 = *(const s16x8*)&prow1[quad * 8];
            s16x8 pf11 = *(const s16x8*)&prow1[32 + quad * 8];
            __builtin_amdgcn_s_setprio(1);
#pragma unroll
            for (int mb = 0; mb < 4; mb++) {
                oa0[mb].v = __builtin_amdgcn_mfma_f32_16x16x32_bf16(vf0[mb], pf00, oa0[mb].v, 0, 0, 0);
                oa1[mb].v = __builtin_amdgcn_mfma_f32_16x16x32_bf16(vf0[mb], pf10, oa1[mb].v, 0, 0, 0);
            }
#pragma unroll
            for (int mb = 0; mb < 4; mb++) {
                oa0[mb].v = __builtin_amdgcn_mfma_f32_16x16x32_bf16(vf1[mb], pf01, oa0[mb].v, 0, 0, 0);
                oa1[mb].v = __builtin_amdgcn_mfma_f32_16x16x32_bf16(vf1[mb], pf11, oa1[mb].v, 0, 0, 0);
            }
            __builtin_amdgcn_s_setprio(0);
            if (kt + 1 < nkt) loadV(kt + 1);   // overwrite vf; WAR after last use
        }

        // ---- lsum reduction: components + across quads (kv partitioned) ----
        float lsum0 = (lsa0.e[0] + lsa0.e[1]) + (lsa0.e[2] + lsa0.e[3]);
        float lsum1 = (lsa1.e[0] + lsa1.e[1]) + (lsa1.e[2] + lsa1.e[3]);
        lsum0 += __shfl_xor(lsum0, 16, 64);
        lsum0 += __shfl_xor(lsum0, 32, 64);
        lsum1 += __shfl_xor(lsum1, 16, 64);
        lsum1 += __shfl_xor(lsum1, 32, 64);

        // ---- epilogue (wave owns its rows fully: no combine, no barrier) ----
#pragma unroll
        for (int nq = 0; nq < 2; nq++) {
            const float rl = 1.0f / (nq ? lsum1 : lsum0);
            const int qrow = qs + nq * 16 + l15;
            float* orow = outg + ((size_t)bh * SQ + qrow) * DH;
#pragma unroll
            for (int mb = 0; mb < 4; mb++) {
                const int d0 = mb * 16 + quad * 4;
                const F4& o = nq ? oa1[mb] : oa0[mb];
                *(float4*)(orow + d0) = make_float4(o.e[0] * rl, o.e[1] * rl,
                                                    o.e[2] * rl, o.e[3] * rl);
            }
        }
    }
}

// ---- fallback (no workspace): self-contained, K/V staged through LDS ----
__global__ __launch_bounds__(256, 4)
void attn_fallback(const float* __restrict__ qg, const float* __restrict__ kg,
                   const float* __restrict__ vg, const float* __restrict__ rotg,
                   float* __restrict__ outg)
{
    const int x  = blockIdx.x;
    const int qt = (x & 1) ? (31 - (x >> 1)) : (x >> 1);
    const int bh = blockIdx.y;
    const int bb = bh >> 4, hh = bh & 15;
    const int bkv = bb * 4 + (hh >> 2);
    const int qs = qt * 64;

    const int tid = threadIdx.x;
    const int wv = tid >> 6, lane = tid & 63;
    const int l15 = lane & 15, quad = lane >> 4;
    const int swl = (l15 & 7) << 3;

    __shared__ __align__(16) short QPs[64 * 64];
    __shared__ __align__(16) short Ks[2][BN * 64];
    __shared__ __align__(16) short Vt[2][DH * 64];

    const size_t kvbase = ((size_t)bkv * SQ) * DH;
    const int nkt = (qt / 4 + 1) * 4;
    const int qglob = qs + wv * 16 + l15;

    {   // Q rope inline
        int rr = tid >> 2, c0 = (tid & 3) * 8;
        int srow = qs + rr;
        const float* gq = qg + ((size_t)bh * SQ + srow) * DH;
        float a[8], b[8];
        *(float4*)&a[0] = *(const float4*)(gq + c0);
        *(float4*)&a[4] = *(const float4*)(gq + c0 + 4);
        *(float4*)&b[0] = *(const float4*)(gq + c0 + 32);
        *(float4*)&b[4] = *(const float4*)(gq + c0 + 36);
        U8 o0, o1;
#pragma unroll
        for (int j = 0; j < 8; j++) {
            float2 sc = fsincos(rotg[(size_t)srow * DH + c0 + j]);
            o0.e[j] = (short)f2bf(a[j] * sc.y - b[j] * sc.x);
            o1.e[j] = (short)f2bf(b[j] * sc.y + a[j] * sc.x);
        }
        int sw2 = (rr & 7) << 3;
        *(s16x8*)&QPs[rr * 64 + (c0 ^ sw2)]        = o0.v;
        *(s16x8*)&QPs[rr * 64 + ((c0 + 32) ^ sw2)] = o1.v;
    }
    __syncthreads();

    s16x8 qf[2];
#pragma unroll
    for (int ks = 0; ks < 2; ks++)
        qf[ks] = *(const s16x8*)&QPs[(wv * 16 + l15) * 64 + ((ks * 32 + quad * 8) ^ swl)];

    F4 oa[4];
#pragma unroll
    for (int mb = 0; mb < 4; mb++) oa[mb].v = (f32x4){0.f, 0.f, 0.f, 0.f};
    float lsum = 0.f;

    for (int kt = 0; kt < nkt; kt++) {
        const int cb = kt & 1;
        {   // K rope inline
            int rr = tid >> 2, c0 = (tid & 3) * 8;
            int srow = kt * BN + rr;
            const float* gk = kg + kvbase + (size_t)srow * DH;
            float a[8], b[8];
            *(float4*)&a[0] = *(const float4*)(gk + c0);
            *(float4*)&a[4] = *(const float4*)(gk + c0 + 4);
            *(float4*)&b[0] = *(const float4*)(gk + c0 + 32);
            *(float4*)&b[4] = *(const float4*)(gk + c0 + 36);
            U8 o0, o1;
#pragma unroll
            for (int j = 0; j < 8; j++) {
                float2 sc = fsincos(rotg[(size_t)(srow & (SQ - 1)) * DH + c0 + j]);
                o0.e[j] = (short)f2bf(a[j] * sc.y - b[j] * sc.x);
                o1.e[j] = (short)f2bf(b[j] * sc.y + a[j] * sc.x);
            }
            int sw2 = (rr & 7) << 3;
            *(s16x8*)&Ks[cb][rr * 64 + (c0 ^ sw2)]        = o0.v;
            *(s16x8*)&Ks[cb][rr * 64 + ((c0 + 32) ^ sw2)] = o1.v;
        }
        {   // V transpose inline
            int rr = tid >> 2, c0 = (tid & 3) * 16;
            const float* gv = vg + kvbase + (size_t)(kt * BN + rr) * DH;
            float vv[16];
#pragma unroll
            for (int t = 0; t < 4; t++)
                *(float4*)&vv[t * 4] = *(const float4*)(gv + c0 + t * 4);
#pragma unroll
            for (int j = 0; j < 16; j++) {
                int d = c0 + j;
                Vt[cb][d * 64 + (rr ^ ((d & 7) << 3))] = (short)f2bf(vv[j]);
            }
        }
        __syncthreads();

        F4 sa[4];
#pragma unroll
        for (int mb = 0; mb < 4; mb++) sa[mb].v = (f32x4){0.f, 0.f, 0.f, 0.f};
#pragma unroll
        for (int ks = 0; ks < 2; ks++)
#pragma unroll
            for (int mb = 0; mb < 4; mb++) {
                s16x8 kf = *(const s16x8*)&Ks[cb][(mb * 16 + l15) * 64 + ((ks * 32 + quad * 8) ^ swl)];
                sa[mb].v = __builtin_amdgcn_mfma_f32_16x16x32_bf16(kf, qf[ks], sa[mb].v, 0, 0, 0);
            }

        F4 pa[4];
#pragma unroll
        for (int mb = 0; mb < 4; mb++)
#pragma unroll
            for (int c = 0; c < 4; c++) {
                float t  = sa[mb].e[c] * K1F;
                float w2 = t * t;
                float poly = fmaf(w2, fmaf(w2, KPAF, KPBF), 1.0f);
                pa[mb].e[c] = exp2hw(fmaf(t, poly, -KEF));
            }
        if (kt == 31 && qglob < SPECIAL_START) {
#pragma unroll
            for (int mb = 0; mb < 4; mb++)
#pragma unroll
                for (int c = 0; c < 4; c++) {
                    int kvglob = kt * BN + mb * 16 + quad * 4 + c;
                    if (kvglob >= SPECIAL_START) pa[mb].e[c] = 0.f;
                }
        }
        short* prow = &QPs[(wv * 16 + l15) * 64];
#pragma unroll
        for (int mb = 0; mb < 4; mb++) {
            lsum += (pa[mb].e[0] + pa[mb].e[1]) + (pa[mb].e[2] + pa[mb].e[3]);
            uint2 pw = make_uint2(pkbf(pa[mb].e[0], pa[mb].e[1]),
                                  pkbf(pa[mb].e[2], pa[mb].e[3]));
            *(uint2*)&prow[(mb * 16 + quad * 4) ^ swl] = pw;
        }
#pragma unroll
        for (int ks = 0; ks < 2; ks++) {
            s16x8 pf = *(const s16x8*)&prow[(ks * 32 + quad * 8) ^ swl];
#pragma unroll
            for (int mb = 0; mb < 4; mb++) {
                s16x8 vf = *(const s16x8*)&Vt[cb][(mb * 16 + l15) * 64 + ((ks * 32 + quad * 8) ^ swl)];
                oa[mb].v = __builtin_amdgcn_mfma_f32_16x16x32_bf16(vf, pf, oa[mb].v, 0, 0, 0);
            }
        }
        __syncthreads();
    }

    lsum += __shfl_xor(lsum, 16, 64);
    lsum += __shfl_xor(lsum, 32, 64);

    float rl = 1.0f / lsum;
    int qrow = qs + wv * 16 + l15;
    float* orow = outg + ((size_t)bh * SQ + qrow) * DH;
#pragma unroll
    for (int mb = 0; mb < 4; mb++) {
        int d0 = mb * 16 + quad * 4;
        *(float4*)(orow + d0) = make_float4(oa[mb].e[0] * rl, oa[mb].e[1] * rl,
                                            oa[mb].e[2] * rl, oa[mb].e[3] * rl);
    }
}

extern "C" void kernel_launch(void* const* d_in, const int* in_sizes, int n_in,
                              void* d_out, int out_size, void* d_ws, size_t ws_size,
                              hipStream_t stream) {
    const float* q   = (const float*)d_in[0];
    const float* k   = (const float*)d_in[1];
    const float* v   = (const float*)d_in[2];
    const float* rot = (const float*)d_in[3];
    float* out = (float*)d_out;

    char* w = (char*)d_ws;
    const size_t k_bytes = (size_t)NKV * SQ * DH * sizeof(u16);     // 2 MiB
    const size_t v_bytes = k_bytes;                                 // 2 MiB
    u16* kp = (u16*)w;
    u16* vp = (u16*)(w + k_bytes);
    uint32_t* cnt = (uint32_t*)(w + k_bytes + v_bytes);

    if (ws_size >= k_bytes + v_bytes + sizeof(uint32_t)) {
        hipLaunchKernelGGL(prep_kernel, dim3(VTILES + KBLK), dim3(256), 0, stream,
                           k, v, rot, kp, vp, cnt);
        hipLaunchKernelGGL(attn_fast, dim3(ATTN_BLOCKS), dim3(256), 0, stream,
                           q, rot, kp, vp, cnt, out);
    } else {
        hipLaunchKernelGGL(attn_fallback, dim3(32, NBH), dim3(256), 0, stream,
                           q, k, v, rot, out);
    }
}

// Round 6
// 129.702 us; speedup vs baseline: 1.6587x; 1.6587x over previous
//
#include <hip/hip_runtime.h>
#include <stdint.h>

typedef unsigned short u16;
typedef short s16x8 __attribute__((ext_vector_type(8)));
typedef float f32x4 __attribute__((ext_vector_type(4)));

#define SQ 2048
#define DH 64
#define BN 64
#define STR 72             // prep-only LDS transpose stride (shorts)
#define SPECIAL_START 2040
#define NBH 32             // b*h
#define NKV 8              // b*hk
#define NQP 16             // qt-pair index 0..15 (128 q-rows per item)
#define NITEMS (NBH * NQP) // 512 work items
#define ATTN_GRID 512      // 2 blocks/CU; queue rebalances the causal skew
// softclamp+softmax folded to exp2: p = 2^( t*poly(t*t) - KEF ), t = s * K1F
#define K1F  0.18033688011112043f    // 0.125 * log2(e)
#define KPAF 4.9244826e-9f           // (2/15)*k^2, k = (0.02/log2e)^2
#define KPBF -6.406040185576019e-5f  // -k/3
#define KEF  36.067376022224085f     // 25 * log2(e)  (constant softmax shift = 25)

union U8 { s16x8 v; short e[8]; };
union F4 { f32x4 v; float e[4]; };

__device__ __forceinline__ u16 f2bf(float x) {  // round-to-nearest-even
    uint32_t u = __float_as_uint(x);
    return (u16)((u + 0x7fffu + ((u >> 16) & 1u)) >> 16);
}
__device__ __forceinline__ uint32_t pkbf(float a, float b) {  // pack 2 bf16, 1 instr
    uint32_t r;
    asm("v_cvt_pk_bf16_f32 %0, %1, %2" : "=v"(r) : "v"(a), "v"(b));
    return r;
}
__device__ __forceinline__ float exp2hw(float x) {
    float r; asm("v_exp_f32 %0, %1" : "=v"(r) : "v"(x)); return r;
}
__device__ __forceinline__ float2 fsincos(float ang) {  // {sin, cos}, fast HW path
    float r = ang * 0.15915494309189535f;   // radians -> revolutions
    r -= floorf(r);
    float s, c;
    asm("v_sin_f32 %0, %1" : "=v"(s) : "v"(r));
    asm("v_cos_f32 %0, %1" : "=v"(c) : "v"(r));
    return make_float2(s, c);
}
// async global->LDS, 16B per lane; LDS dest = wave-uniform base + lane*16
__device__ __forceinline__ void gl_lds16(const void* g, void* l) {
    __builtin_amdgcn_global_load_lds(
        (const __attribute__((address_space(1))) uint32_t*)g,
        (__attribute__((address_space(3))) uint32_t*)l, 16, 0, 0);
}

// ---- prep: V tiles (transpose to [tile][d][kv]) + K rope rows (bf16) ----
#define VTILES (NKV * 32)                 // 256 tile-blocks
#define RK (NKV * SQ)                     // 16384 K rows
#define KBLK (RK / 32)                    // 512 row-blocks (32 rows each)
__global__ __launch_bounds__(256)
void prep_kernel(const float* __restrict__ kg, const float* __restrict__ vg,
                 const float* __restrict__ rotg,
                 u16* __restrict__ kp, u16* __restrict__ vp,
                 uint32_t* __restrict__ cnt)
{
    const int tid = threadIdx.x;
    if (blockIdx.x == 0 && tid == 0) *cnt = 0u;
    if (blockIdx.x < VTILES) {
        __shared__ short Vls[64 * STR];
        const int tile = blockIdx.x;                   // bkv*32 + kt
        const float* src = vg + ((size_t)(tile >> 5) * SQ + (size_t)(tile & 31) * 64) * DH;
        {
            int kv = tid >> 2, c0 = (tid & 3) * 16;
            const float* s4 = src + (size_t)kv * DH + c0;
            float4 f0 = *(const float4*)(s4);
            float4 f1 = *(const float4*)(s4 + 4);
            float4 f2 = *(const float4*)(s4 + 8);
            float4 f3 = *(const float4*)(s4 + 12);
            uint4 w0 = make_uint4(pkbf(f0.x, f0.y), pkbf(f0.z, f0.w),
                                  pkbf(f1.x, f1.y), pkbf(f1.z, f1.w));
            uint4 w1 = make_uint4(pkbf(f2.x, f2.y), pkbf(f2.z, f2.w),
                                  pkbf(f3.x, f3.y), pkbf(f3.z, f3.w));
            *(uint4*)&Vls[kv * STR + c0]     = w0;
            *(uint4*)&Vls[kv * STR + c0 + 8] = w1;
        }
        __syncthreads();
        {
            int d = tid >> 2, c0 = (tid & 3) * 16;
            U8 o0, o1;
#pragma unroll
            for (int j = 0; j < 16; j++)
                (j < 8 ? o0 : o1).e[j & 7] = Vls[(c0 + j) * STR + d];  // transpose
            u16* dst = vp + (((size_t)tile * 64 + d) << 6) + c0;
            *(s16x8*)dst       = o0.v;
            *(s16x8*)(dst + 8) = o1.v;
        }
    } else {
        int bx = blockIdx.x - VTILES;
        int r8 = tid >> 3, c0 = (tid & 7) * 4;      // c0 in 0..28 (<32)
        int r = bx * 32 + r8;                        // r in [0, RK)
        const int s = r & (SQ - 1);
        const float* src = kg + (size_t)r * DH;
        u16*         dst = kp + (size_t)r * DH;
        float4 a  = *(const float4*)(src + c0);
        float4 b  = *(const float4*)(src + c0 + 32);
        float4 rv = *(const float4*)(rotg + (size_t)s * DH + c0);
        float2 s0 = fsincos(rv.x), s1 = fsincos(rv.y),
               s2 = fsincos(rv.z), s3 = fsincos(rv.w);
        float lo0 = a.x * s0.y - b.x * s0.x, hi0 = b.x * s0.y + a.x * s0.x;
        float lo1 = a.y * s1.y - b.y * s1.x, hi1 = b.y * s1.y + a.y * s1.x;
        float lo2 = a.z * s2.y - b.z * s2.x, hi2 = b.z * s2.y + a.z * s2.x;
        float lo3 = a.w * s3.y - b.w * s3.x, hi3 = b.w * s3.y + a.w * s3.x;
        *(uint2*)(dst + c0)      = make_uint2(pkbf(lo0, lo1), pkbf(lo2, lo3));
        *(uint2*)(dst + c0 + 32) = make_uint2(pkbf(hi0, hi1), pkbf(hi2, hi3));
    }
}

// ---- attn: 4 waves / 256 threads; block = 128 q-rows (one qp item); each
// wave owns 32 q-rows (2 q-tiles) so every K/V LDS fragment feeds 2 MFMAs.
// K/V staged by global_load_lds into double-buffered LDS: linear LDS dest,
// INVERSE-swizzled global source (rule 21), one barrier per ktile; stage of
// kt+1 is issued a full compute phase before its barrier drain. Q roped
// straight into registers. Register budget pinned (waves_per_eu 3..4) so the
// ~130-reg live set does NOT spill (R4's 30MB scratch traffic).
// S^T = K.Q^T via mfma(A=K,B=Q)   -> C: col(l15)=q, row(quad*4+c)=kv
// O^T = V^T.P via mfma(A=Vt,B=P)  -> C: col(l15)=q, row(quad*4+c)=d
__global__ __launch_bounds__(256)
__attribute__((amdgpu_waves_per_eu(3, 4)))
void attn_fast(const float* __restrict__ qg, const float* __restrict__ rotg,
               const u16* __restrict__ kp, const u16* __restrict__ vp,
               uint32_t* __restrict__ cnt, float* __restrict__ outg)
{
    const int tid = threadIdx.x;
    const int wv = tid >> 6, lane = tid & 63;
    const int l15 = lane & 15, quad = lane >> 4;
    const int swl = (l15 & 7) << 3;            // fragment-row swizzle (shorts)

    __shared__ __align__(16) u16 Ks[2][4096];  // 16 KB dbuf
    __shared__ __align__(16) u16 Vt[2][4096];  // 16 KB dbuf
    __shared__ __align__(16) short Ps[128 * 64]; // 16 KB, wave-private rows
    __shared__ int s_w;

    // staging geometry: slot s in {0,1}; row = wv*16 + s*8 + (lane>>3);
    // LDS linear short-offset = (wv*2+s)*512 + lane*8 (HW: base + lane*16B);
    // global col pre-swizzled so LDS[row][csw] = G[row][csw ^ ((row&7)<<3)]
    const int gcol = (((lane & 7) ^ (lane >> 3)) << 3);
    const int goff0 = ((wv * 16 + (lane >> 3)) << 6) + gcol;
    const int goff1 = goff0 + (8 << 6);
    const int lds0 = (wv * 2) * 512;           // wave-uniform
    const int lds1 = lds0 + 512;

    short* prow0 = &Ps[(wv * 32 + l15) * 64];
    short* prow1 = &Ps[(wv * 32 + 16 + l15) * 64];

    for (;;) {
        __syncthreads();                       // protect s_w + LDS reuse
        if (tid == 0) s_w = (int)atomicAdd(cnt, 1u);
        __syncthreads();
        const int w = s_w;
        if (w >= NITEMS) break;
        const int qp = (NQP - 1) - (w >> 5);   // heavy-first
        const int u  = w & 31, bkv = u >> 2;   // consecutive pops share bkv
        const int bh = ((bkv >> 2) << 4) | ((bkv & 3) << 2) | (u & 3);
        const int nkt = (((qp >> 1) + 1)) << 2;  // 4..32
        const int qrow0 = qp * 128 + wv * 32;

        const u16* kbase = kp + (size_t)bkv * (SQ * DH);
        const u16* vbase = vp + (size_t)bkv * (SQ * DH);
        auto stage = [&](int kt, int cb) {
            const u16* tk = kbase + ((size_t)kt << 12);
            const u16* tv = vbase + ((size_t)kt << 12);
            gl_lds16(tk + goff0, &Ks[cb][lds0]);
            gl_lds16(tk + goff1, &Ks[cb][lds1]);
            gl_lds16(tv + goff0, &Vt[cb][lds0]);
            gl_lds16(tv + goff1, &Vt[cb][lds1]);
        };
        stage(0, 0);   // tile-0 DMA flies under the Q rope below

        // ---- Q rope -> registers ----
        s16x8 qf[2][2];
#pragma unroll
        for (int nq = 0; nq < 2; nq++) {
            const int srow = qrow0 + nq * 16 + l15;
            const float* gq = qg + ((size_t)bh * SQ + srow) * DH + quad * 8;
            float a[8], b[8];
            *(float4*)&a[0] = *(const float4*)(gq);
            *(float4*)&a[4] = *(const float4*)(gq + 4);
            *(float4*)&b[0] = *(const float4*)(gq + 32);
            *(float4*)&b[4] = *(const float4*)(gq + 36);
            const float* rrow = rotg + (size_t)srow * DH + quad * 8;
            float lo[8], hi[8];
#pragma unroll
            for (int j = 0; j < 8; j++) {
                float2 sc = fsincos(rrow[j]);
                lo[j] = a[j] * sc.y - b[j] * sc.x;
                hi[j] = b[j] * sc.y + a[j] * sc.x;
            }
            U8 q0, q1;
#pragma unroll
            for (int j = 0; j < 4; j++) {
                ((uint32_t*)&q0.v)[j] = pkbf(lo[2 * j], lo[2 * j + 1]);
                ((uint32_t*)&q1.v)[j] = pkbf(hi[2 * j], hi[2 * j + 1]);
            }
            qf[nq][0] = q0.v;
            qf[nq][1] = q1.v;
        }

        F4 oa[2][4];
#pragma unroll
        for (int nq = 0; nq < 2; nq++)
#pragma unroll
            for (int mb = 0; mb < 4; mb++) oa[nq][mb].v = (f32x4){0.f, 0.f, 0.f, 0.f};
        F4 lsa0, lsa1;
        lsa0.v = (f32x4){0.f, 0.f, 0.f, 0.f};
        lsa1.v = (f32x4){0.f, 0.f, 0.f, 0.f};

        __syncthreads();   // tile-0 staged (drains vmcnt)
        int cb = 0;

        for (int kt = 0; kt < nkt; kt++) {
            if (kt + 1 < nkt) stage(kt + 1, cb ^ 1);  // full phase before drain

            // ---- QK^T: S^T[kv][q]; each kf feeds both q-tiles ----
            F4 sa[2][4];
            __builtin_amdgcn_s_setprio(1);
#pragma unroll
            for (int ks = 0; ks < 2; ks++)
#pragma unroll
                for (int mb = 0; mb < 4; mb++) {
                    s16x8 kf = *(const s16x8*)&Ks[cb][(mb * 16 + l15) * 64 + ((ks * 32 + quad * 8) ^ swl)];
                    sa[0][mb].v = __builtin_amdgcn_mfma_f32_16x16x32_bf16(
                        kf, qf[0][ks], ks ? sa[0][mb].v : (f32x4){0.f, 0.f, 0.f, 0.f}, 0, 0, 0);
                    sa[1][mb].v = __builtin_amdgcn_mfma_f32_16x16x32_bf16(
                        kf, qf[1][ks], ks ? sa[1][mb].v : (f32x4){0.f, 0.f, 0.f, 0.f}, 0, 0, 0);
                }
            __builtin_amdgcn_s_setprio(0);

            // ---- softclamp + constant-shift softmax (exp2-folded, vectorized) ----
            const int last = (kt == 31);
#pragma unroll
            for (int nq = 0; nq < 2; nq++) {
                const int qglob = qrow0 + nq * 16 + l15;
                short* prow = nq ? prow1 : prow0;
#pragma unroll
                for (int mb = 0; mb < 4; mb++) {
                    F4 t, w2, py, pa;
                    t.v  = sa[nq][mb].v * K1F;
                    w2.v = t.v * t.v;
                    py.v = w2.v * KPAF + KPBF;
                    py.v = w2.v * py.v + 1.0f;
                    t.v  = t.v * py.v - KEF;
                    pa.e[0] = exp2hw(t.e[0]);
                    pa.e[1] = exp2hw(t.e[1]);
                    pa.e[2] = exp2hw(t.e[2]);
                    pa.e[3] = exp2hw(t.e[3]);
                    if (last && qglob < SPECIAL_START) {   // special-token mask
#pragma unroll
                        for (int c = 0; c < 4; c++) {
                            int kvglob = kt * BN + mb * 16 + quad * 4 + c;
                            if (kvglob >= SPECIAL_START) pa.e[c] = 0.f;
                        }
                    }
                    if (nq) lsa1.v = lsa1.v + pa.v; else lsa0.v = lsa0.v + pa.v;
                    uint2 pw = make_uint2(pkbf(pa.e[0], pa.e[1]),
                                          pkbf(pa.e[2], pa.e[3]));
                    *(uint2*)&prow[(mb * 16 + quad * 4) ^ swl] = pw;  // wave-private
                }
            }

            // ---- PV: O^T[d][q] += Vt.P; each vf feeds both q-tiles ----
            s16x8 pf00 = *(const s16x8*)&prow0[(quad * 8) ^ swl];
            s16x8 pf01 = *(const s16x8*)&prow0[(32 + quad * 8) ^ swl];
            s16x8 pf10 = *(const s16x8*)&prow1[(quad * 8) ^ swl];
            s16x8 pf11 = *(const s16x8*)&prow1[(32 + quad * 8) ^ swl];
            __builtin_amdgcn_s_setprio(1);
#pragma unroll
            for (int mb = 0; mb < 4; mb++) {
                s16x8 vf = *(const s16x8*)&Vt[cb][(mb * 16 + l15) * 64 + ((quad * 8) ^ swl)];
                oa[0][mb].v = __builtin_amdgcn_mfma_f32_16x16x32_bf16(vf, pf00, oa[0][mb].v, 0, 0, 0);
                oa[1][mb].v = __builtin_amdgcn_mfma_f32_16x16x32_bf16(vf, pf10, oa[1][mb].v, 0, 0, 0);
            }
#pragma unroll
            for (int mb = 0; mb < 4; mb++) {
                s16x8 vf = *(const s16x8*)&Vt[cb][(mb * 16 + l15) * 64 + ((32 + quad * 8) ^ swl)];
                oa[0][mb].v = __builtin_amdgcn_mfma_f32_16x16x32_bf16(vf, pf01, oa[0][mb].v, 0, 0, 0);
                oa[1][mb].v = __builtin_amdgcn_mfma_f32_16x16x32_bf16(vf, pf11, oa[1][mb].v, 0, 0, 0);
            }
            __builtin_amdgcn_s_setprio(0);

            __syncthreads();   // buf[cb] reads done; kt+1 DMA landed
            cb ^= 1;
        }

        // ---- lsum reduction: components + across quads (kv partitioned) ----
        float lsum0 = (lsa0.e[0] + lsa0.e[1]) + (lsa0.e[2] + lsa0.e[3]);
        float lsum1 = (lsa1.e[0] + lsa1.e[1]) + (lsa1.e[2] + lsa1.e[3]);
        lsum0 += __shfl_xor(lsum0, 16, 64);
        lsum0 += __shfl_xor(lsum0, 32, 64);
        lsum1 += __shfl_xor(lsum1, 16, 64);
        lsum1 += __shfl_xor(lsum1, 32, 64);

        // ---- epilogue (wave owns its rows fully) ----
#pragma unroll
        for (int nq = 0; nq < 2; nq++) {
            const float rl = 1.0f / (nq ? lsum1 : lsum0);
            const int qrow = qrow0 + nq * 16 + l15;
            float* orow = outg + ((size_t)bh * SQ + qrow) * DH;
#pragma unroll
            for (int mb = 0; mb < 4; mb++) {
                const int d0 = mb * 16 + quad * 4;
                const F4& o = oa[nq][mb];
                *(float4*)(orow + d0) = make_float4(o.e[0] * rl, o.e[1] * rl,
                                                    o.e[2] * rl, o.e[3] * rl);
            }
        }
    }
}

// ---- fallback (no workspace): self-contained, K/V staged through LDS ----
__global__ __launch_bounds__(256, 4)
void attn_fallback(const float* __restrict__ qg, const float* __restrict__ kg,
                   const float* __restrict__ vg, const float* __restrict__ rotg,
                   float* __restrict__ outg)
{
    const int x  = blockIdx.x;
    const int qt = (x & 1) ? (31 - (x >> 1)) : (x >> 1);
    const int bh = blockIdx.y;
    const int bb = bh >> 4, hh = bh & 15;
    const int bkv = bb * 4 + (hh >> 2);
    const int qs = qt * 64;

    const int tid = threadIdx.x;
    const int wv = tid >> 6, lane = tid & 63;
    const int l15 = lane & 15, quad = lane >> 4;
    const int swl = (l15 & 7) << 3;

    __shared__ __align__(16) short QPs[64 * 64];
    __shared__ __align__(16) short Ks[2][BN * 64];
    __shared__ __align__(16) short Vt[2][DH * 64];

    const size_t kvbase = ((size_t)bkv * SQ) * DH;
    const int nkt = (qt / 4 + 1) * 4;
    const int qglob = qs + wv * 16 + l15;

    {   // Q rope inline
        int rr = tid >> 2, c0 = (tid & 3) * 8;
        int srow = qs + rr;
        const float* gq = qg + ((size_t)bh * SQ + srow) * DH;
        float a[8], b[8];
        *(float4*)&a[0] = *(const float4*)(gq + c0);
        *(float4*)&a[4] = *(const float4*)(gq + c0 + 4);
        *(float4*)&b[0] = *(const float4*)(gq + c0 + 32);
        *(float4*)&b[4] = *(const float4*)(gq + c0 + 36);
        U8 o0, o1;
#pragma unroll
        for (int j = 0; j < 8; j++) {
            float2 sc = fsincos(rotg[(size_t)srow * DH + c0 + j]);
            o0.e[j] = (short)f2bf(a[j] * sc.y - b[j] * sc.x);
            o1.e[j] = (short)f2bf(b[j] * sc.y + a[j] * sc.x);
        }
        int sw2 = (rr & 7) << 3;
        *(s16x8*)&QPs[rr * 64 + (c0 ^ sw2)]        = o0.v;
        *(s16x8*)&QPs[rr * 64 + ((c0 + 32) ^ sw2)] = o1.v;
    }
    __syncthreads();

    s16x8 qf[2];
#pragma unroll
    for (int ks = 0; ks < 2; ks++)
        qf[ks] = *(const s16x8*)&QPs[(wv * 16 + l15) * 64 + ((ks * 32 + quad * 8) ^ swl)];

    F4 oa[4];
#pragma unroll
    for (int mb = 0; mb < 4; mb++) oa[mb].v = (f32x4){0.f, 0.f, 0.f, 0.f};
    float lsum = 0.f;

    for (int kt = 0; kt < nkt; kt++) {
        const int cb = kt & 1;
        {   // K rope inline
            int rr = tid >> 2, c0 = (tid & 3) * 8;
            int srow = kt * BN + rr;
            const float* gk = kg + kvbase + (size_t)srow * DH;
            float a[8], b[8];
            *(float4*)&a[0] = *(const float4*)(gk + c0);
            *(float4*)&a[4] = *(const float4*)(gk + c0 + 4);
            *(float4*)&b[0] = *(const float4*)(gk + c0 + 32);
            *(float4*)&b[4] = *(const float4*)(gk + c0 + 36);
            U8 o0, o1;
#pragma unroll
            for (int j = 0; j < 8; j++) {
                float2 sc = fsincos(rotg[(size_t)(srow & (SQ - 1)) * DH + c0 + j]);
                o0.e[j] = (short)f2bf(a[j] * sc.y - b[j] * sc.x);
                o1.e[j] = (short)f2bf(b[j] * sc.y + a[j] * sc.x);
            }
            int sw2 = (rr & 7) << 3;
            *(s16x8*)&Ks[cb][rr * 64 + (c0 ^ sw2)]        = o0.v;
            *(s16x8*)&Ks[cb][rr * 64 + ((c0 + 32) ^ sw2)] = o1.v;
        }
        {   // V transpose inline
            int rr = tid >> 2, c0 = (tid & 3) * 16;
            const float* gv = vg + kvbase + (size_t)(kt * BN + rr) * DH;
            float vv[16];
#pragma unroll
            for (int t = 0; t < 4; t++)
                *(float4*)&vv[t * 4] = *(const float4*)(gv + c0 + t * 4);
#pragma unroll
            for (int j = 0; j < 16; j++) {
                int d = c0 + j;
                Vt[cb][d * 64 + (rr ^ ((d & 7) << 3))] = (short)f2bf(vv[j]);
            }
        }
        __syncthreads();

        F4 sa[4];
#pragma unroll
        for (int mb = 0; mb < 4; mb++) sa[mb].v = (f32x4){0.f, 0.f, 0.f, 0.f};
#pragma unroll
        for (int ks = 0; ks < 2; ks++)
#pragma unroll
            for (int mb = 0; mb < 4; mb++) {
                s16x8 kf = *(const s16x8*)&Ks[cb][(mb * 16 + l15) * 64 + ((ks * 32 + quad * 8) ^ swl)];
                sa[mb].v = __builtin_amdgcn_mfma_f32_16x16x32_bf16(kf, qf[ks], sa[mb].v, 0, 0, 0);
            }

        F4 pa[4];
#pragma unroll
        for (int mb = 0; mb < 4; mb++)
#pragma unroll
            for (int c = 0; c < 4; c++) {
                float t  = sa[mb].e[c] * K1F;
                float w2 = t * t;
                float poly = fmaf(w2, fmaf(w2, KPAF, KPBF), 1.0f);
                pa[mb].e[c] = exp2hw(fmaf(t, poly, -KEF));
            }
        if (kt == 31 && qglob < SPECIAL_START) {
#pragma unroll
            for (int mb = 0; mb < 4; mb++)
#pragma unroll
                for (int c = 0; c < 4; c++) {
                    int kvglob = kt * BN + mb * 16 + quad * 4 + c;
                    if (kvglob >= SPECIAL_START) pa[mb].e[c] = 0.f;
                }
        }
        short* prow = &QPs[(wv * 16 + l15) * 64];
#pragma unroll
        for (int mb = 0; mb < 4; mb++) {
            lsum += (pa[mb].e[0] + pa[mb].e[1]) + (pa[mb].e[2] + pa[mb].e[3]);
            uint2 pw = make_uint2(pkbf(pa[mb].e[0], pa[mb].e[1]),
                                  pkbf(pa[mb].e[2], pa[mb].e[3]));
            *(uint2*)&prow[(mb * 16 + quad * 4) ^ swl] = pw;
        }
#pragma unroll
        for (int ks = 0; ks < 2; ks++) {
            s16x8 pf = *(const s16x8*)&prow[(ks * 32 + quad * 8) ^ swl];
#pragma unroll
            for (int mb = 0; mb < 4; mb++) {
                s16x8 vf = *(const s16x8*)&Vt[cb][(mb * 16 + l15) * 64 + ((ks * 32 + quad * 8) ^ swl)];
                oa[mb].v = __builtin_amdgcn_mfma_f32_16x16x32_bf16(vf, pf, oa[mb].v, 0, 0, 0);
            }
        }
        __syncthreads();
    }

    lsum += __shfl_xor(lsum, 16, 64);
    lsum += __shfl_xor(lsum, 32, 64);

    float rl = 1.0f / lsum;
    int qrow = qs + wv * 16 + l15;
    float* orow = outg + ((size_t)bh * SQ + qrow) * DH;
#pragma unroll
    for (int mb = 0; mb < 4; mb++) {
        int d0 = mb * 16 + quad * 4;
        *(float4*)(orow + d0) = make_float4(oa[mb].e[0] * rl, oa[mb].e[1] * rl,
                                            oa[mb].e[2] * rl, oa[mb].e[3] * rl);
    }
}

extern "C" void kernel_launch(void* const* d_in, const int* in_sizes, int n_in,
                              void* d_out, int out_size, void* d_ws, size_t ws_size,
                              hipStream_t stream) {
    const float* q   = (const float*)d_in[0];
    const float* k   = (const float*)d_in[1];
    const float* v   = (const float*)d_in[2];
    const float* rot = (const float*)d_in[3];
    float* out = (float*)d_out;

    char* w = (char*)d_ws;
    const size_t k_bytes = (size_t)NKV * SQ * DH * sizeof(u16);     // 2 MiB
    const size_t v_bytes = k_bytes;                                 // 2 MiB
    u16* kp = (u16*)w;
    u16* vp = (u16*)(w + k_bytes);
    uint32_t* cnt = (uint32_t*)(w + k_bytes + v_bytes);

    if (ws_size >= k_bytes + v_bytes + sizeof(uint32_t)) {
        hipLaunchKernelGGL(prep_kernel, dim3(VTILES + KBLK), dim3(256), 0, stream,
                           k, v, rot, kp, vp, cnt);
        hipLaunchKernelGGL(attn_fast, dim3(ATTN_GRID), dim3(256), 0, stream,
                           q, rot, kp, vp, cnt, out);
    } else {
        hipLaunchKernelGGL(attn_fallback, dim3(32, NBH), dim3(256), 0, stream,
                           q, k, v, rot, out);
    }
}